// Round 16
// baseline (121.837 us; speedup 1.0000x reference)
//
#include <hip/hip_runtime.h>
#include <hip/hip_bf16.h>

using f32x4 = __attribute__((ext_vector_type(4))) float;
using s16x8 = __attribute__((ext_vector_type(8))) short;
using s16x4 = __attribute__((ext_vector_type(4))) short;

#define B_ 2
#define C_ 256
#define N_ 4096
#define LOG2E 1.4426950408889634f

__device__ inline unsigned short f2bf(float f) {
    union { float f; unsigned u; } x{f};
    unsigned r = x.u + 0x7fffu + ((x.u >> 16) & 1u);
    return (unsigned short)(r >> 16);
}

__device__ inline float bf2f(unsigned short u) {
    union { unsigned u; float f; } x{(unsigned)u << 16};
    return x.f;
}

__device__ inline void load_lds16(const void* g, void* l) {
    __builtin_amdgcn_global_load_lds((const __attribute__((address_space(1))) void*)g,
                                     (__attribute__((address_space(3))) void*)l, 16, 0, 0);
}

// ---------------- GroupNorm pass 1 (blocks 0..255) + W cvt (blocks 256..319) ----------------
__global__ __launch_bounds__(256) void gn_stats_kernel(const float* __restrict__ x,
                                                       float* __restrict__ part,
                                                       const float* __restrict__ wq,
                                                       const float* __restrict__ wk,
                                                       const float* __restrict__ wv,
                                                       const float* __restrict__ wp,
                                                       unsigned short* __restrict__ wbf) {
    int blk = blockIdx.x;
    int t = threadIdx.x;
    if (blk >= 256) {
        int bi = blk - 256;
        int g = bi >> 4, chunk = bi & 15;
        const float* src = g == 0 ? wq : g == 1 ? wk : g == 2 ? wv : wp;
        int idx = chunk * 4096 + t * 16;
        for (int i = 0; i < 4; ++i) {
            float4 v = *(const float4*)(src + idx + i * 4);
            s16x4 pk;
            pk[0] = (short)f2bf(v.x); pk[1] = (short)f2bf(v.y);
            pk[2] = (short)f2bf(v.z); pk[3] = (short)f2bf(v.w);
            *(s16x4*)(wbf + g * 65536 + idx + i * 4) = pk;
        }
        return;
    }
    int qtr = blk & 3, grp = (blk >> 2) & 31, b = blk >> 7;
    const float* xb = x + ((size_t)b * C_ + grp * 8) * N_ + qtr * 1024;
    float s = 0.f, sq = 0.f;
    for (int j = 0; j < 8; ++j) {
        float4 v = *(const float4*)(xb + (size_t)j * N_ + t * 4);
        s += v.x + v.y + v.z + v.w;
        sq += v.x * v.x + v.y * v.y + v.z * v.z + v.w * v.w;
    }
    for (int off = 32; off; off >>= 1) {
        s += __shfl_down(s, off);
        sq += __shfl_down(sq, off);
    }
    __shared__ float red[2][4];
    int wid = t >> 6;
    if ((t & 63) == 0) { red[0][wid] = s; red[1][wid] = sq; }
    __syncthreads();
    if (t == 0) {
        part[blk * 2 + 0] = red[0][0] + red[0][1] + red[0][2] + red[0][3];
        part[blk * 2 + 1] = red[1][0] + red[1][1] + red[1][2] + red[1][3];
    }
}

// ---------------- GroupNorm pass 2: normalize + write bf16 [n][c] ----------------
__global__ __launch_bounds__(256) void gn_apply_kernel(const float* __restrict__ x,
                                                       const float* __restrict__ gamma,
                                                       const float* __restrict__ beta,
                                                       const float* __restrict__ part,
                                                       unsigned short* __restrict__ hn_t) {
    int blk = blockIdx.x;
    int qtr = blk & 3, grp = (blk >> 2) & 31, b = blk >> 7;
    int base = (blk & ~3) * 2;
    float S = part[base + 0] + part[base + 2] + part[base + 4] + part[base + 6];
    float Q = part[base + 1] + part[base + 3] + part[base + 5] + part[base + 7];
    float mean = S / 32768.f;
    float rstd = rsqrtf(Q / 32768.f - mean * mean + 1e-6f);

    float gm[8], bt[8];
    for (int j = 0; j < 8; ++j) {
        gm[j] = gamma[grp * 8 + j] * rstd;
        bt[j] = beta[grp * 8 + j] - mean * gm[j];
    }
    const float* xb = x + ((size_t)b * C_ + grp * 8) * N_;
    unsigned short* outp = hn_t + (size_t)b * N_ * C_ + grp * 8;
    int t = threadIdx.x;
    for (int i = 0; i < 4; ++i) {
        int n = qtr * 1024 + i * 256 + t;
        s16x8 pk;
        for (int j = 0; j < 8; ++j) {
            float v = xb[(size_t)j * N_ + n];
            pk[j] = (short)f2bf(v * gm[j] + bt[j]);
        }
        *(s16x8*)(outp + (size_t)n * C_) = pk;
    }
}

// ---------------- GEMM core: 128o x (NB*32)n tile, BK=64, dbuf, global_load_lds ----------------
// NB = 2 -> 128x64 tile (LDS 48KB); NB = 4 -> 128x128 tile (LDS 64KB).
template <int NB>
__device__ inline void gemm_core(const unsigned short* __restrict__ Wg,
                                 const unsigned short* __restrict__ Bg,
                                 int o0, int n0, int t, f32x4 (&acc)[4][NB],
                                 unsigned short (*At)[128 * 64], unsigned short (*Bt)[NB * 32 * 64]) {
    int lane = t & 63, w = t >> 6, l15 = lane & 15, lg = lane >> 4;
    int wo = (w >> 1) * 64, wn = (w & 1) * (NB * 16);
    int aoff[4], boff[NB];
    for (int i = 0; i < 4; ++i) {
        int p = i * 4096 + t * 16;
        int y = p ^ (((p >> 7) & 7) << 4);
        aoff[i] = (o0 + (y >> 7)) * 512 + (y & 127);
    }
    for (int i = 0; i < NB; ++i) {
        int p = i * 4096 + t * 16;
        int y = p ^ (((p >> 7) & 7) << 4);
        boff[i] = (n0 + (y >> 7)) * 512 + (y & 127);
    }
    const char* Wc = (const char*)Wg;
    const char* Bc = (const char*)Bg;
    int cur = 0;
    for (int i = 0; i < 4; ++i)
        load_lds16(Wc + aoff[i], (char*)At[0] + i * 4096 + w * 1024);
    for (int i = 0; i < NB; ++i)
        load_lds16(Bc + boff[i], (char*)Bt[0] + i * 4096 + w * 1024);
    __syncthreads();
    for (int s = 0; s < 4; ++s) {
        if (s < 3) {
            int k2 = (s + 1) * 128;   // k0 * 2 bytes
            for (int i = 0; i < 4; ++i)
                load_lds16(Wc + aoff[i] + k2, (char*)At[cur ^ 1] + i * 4096 + w * 1024);
            for (int i = 0; i < NB; ++i)
                load_lds16(Bc + boff[i] + k2, (char*)Bt[cur ^ 1] + i * 4096 + w * 1024);
        }
        const char* Al = (const char*)At[cur];
        const char* Bl = (const char*)Bt[cur];
        for (int kk = 0; kk < 2; ++kk) {
            s16x8 af[4], bfv[NB];
            for (int mi = 0; mi < 4; ++mi) {
                int row = wo + mi * 16 + l15;
                int lo = row * 128 + kk * 64 + lg * 16;
                af[mi] = *(const s16x8*)(Al + (lo ^ ((row & 7) << 4)));
            }
            for (int ni = 0; ni < NB; ++ni) {
                int row = wn + ni * 16 + l15;
                int lo = row * 128 + kk * 64 + lg * 16;
                bfv[ni] = *(const s16x8*)(Bl + (lo ^ ((row & 7) << 4)));
            }
            for (int mi = 0; mi < 4; ++mi)
                for (int ni = 0; ni < NB; ++ni)
                    acc[mi][ni] = __builtin_amdgcn_mfma_f32_16x16x32_bf16(af[mi], bfv[ni], acc[mi][ni], 0, 0, 0);
        }
        __syncthreads();
        cur ^= 1;
    }
}

// ---------------- fused QKV GEMM, 128x128 tile (z = b*3 + g) ----------------
__global__ __launch_bounds__(256) void qkv_gemm_kernel(const unsigned short* __restrict__ wbf,
                                                       const float* __restrict__ bq,
                                                       const float* __restrict__ bk,
                                                       const float* __restrict__ bv,
                                                       const unsigned short* __restrict__ hn,
                                                       unsigned short* __restrict__ qt,
                                                       unsigned short* __restrict__ kt,
                                                       unsigned char* __restrict__ v8t) {
    __shared__ unsigned short At[2][128 * 64];
    __shared__ unsigned short Bt[2][128 * 64];
    int g = blockIdx.z % 3, b = blockIdx.z / 3;
    const float* bias = g == 0 ? bq : g == 1 ? bk : bv;
    float scale = g == 0 ? 0.0625f * LOG2E : 1.0f;
    int o0 = blockIdx.y * 128, n0 = blockIdx.x * 128;
    int t = threadIdx.x;
    const size_t sz = (size_t)N_ * C_;

    f32x4 acc[4][4];
    for (int mi = 0; mi < 4; ++mi)
        for (int ni = 0; ni < 4; ++ni)
            acc[mi][ni] = (f32x4){0.f, 0.f, 0.f, 0.f};
    gemm_core<4>(wbf + g * 65536, hn + b * sz, o0, n0, t, acc, At, Bt);

    int lane = t & 63, w = t >> 6, l15 = lane & 15, lg = lane >> 4;
    int wo = (w >> 1) * 64, wn = (w & 1) * 64;
    for (int mi = 0; mi < 4; ++mi)
        for (int ni = 0; ni < 4; ++ni)
            for (int r = 0; r < 4; ++r) {
                int o = o0 + wo + mi * 16 + lg * 4 + r;
                int n = n0 + wn + ni * 16 + l15;
                float val = (acc[mi][ni][r] + bias[o]) * scale;
                if (g == 0) {
                    qt[b * sz + (size_t)n * C_ + o] = f2bf(val);
                } else if (g == 1) {
                    // slot = pi^-1(n&31): key bits (r=1:0, f=2, lg=4:3) -> s=16f+4lg+r
                    int slot = ((n >> 2) & 1) * 16 + ((n >> 3) & 3) * 4 + (n & 3);
                    kt[b * sz + (size_t)(n >> 5) * 8192 + (o >> 5) * 1024 + slot * 32 + (o & 31)] = f2bf(val);
                } else {
                    unsigned pk8 = __builtin_amdgcn_cvt_pk_fp8_f32(val, 0.f, 0, false);
                    // bank-conflict-free fp8 V: 8B slot XOR-permuted by channel
                    int key = n & 31;
                    int byteoff = ((((key >> 3) ^ (o >> 2)) & 3) << 3) + (key & 7);
                    v8t[b * sz + (size_t)(n >> 5) * 8192 + o * 32 + byteoff] = (unsigned char)(pk8 & 0xff);
                }
            }
}

// ---------------- output projection GEMM + residual, 128x64 tile ----------------
__global__ __launch_bounds__(256) void proj_gemm_kernel(const unsigned short* __restrict__ wbf,
                                                        const float* __restrict__ bp,
                                                        const unsigned short* __restrict__ ao,
                                                        const float* __restrict__ x,
                                                        float* __restrict__ out) {
    __shared__ unsigned short At[2][128 * 64];
    __shared__ unsigned short Bt[2][64 * 64];
    int b = blockIdx.z;
    int o0 = blockIdx.y * 128, n0 = blockIdx.x * 64;
    int t = threadIdx.x;
    const size_t sz = (size_t)N_ * C_;

    f32x4 acc[4][2];
    for (int mi = 0; mi < 4; ++mi)
        for (int ni = 0; ni < 2; ++ni)
            acc[mi][ni] = (f32x4){0.f, 0.f, 0.f, 0.f};
    gemm_core<2>(wbf + 3 * 65536, ao + b * sz, o0, n0, t, acc, At, Bt);

    int lane = t & 63, w = t >> 6, l15 = lane & 15, lg = lane >> 4;
    int wo = (w >> 1) * 64, wn = (w & 1) * 32;
    for (int mi = 0; mi < 4; ++mi)
        for (int ni = 0; ni < 2; ++ni)
            for (int r = 0; r < 4; ++r) {
                int o = o0 + wo + mi * 16 + lg * 4 + r;
                int n = n0 + wn + ni * 16 + l15;
                size_t idx = b * sz + (size_t)o * N_ + n;
                out[idx] = x[idx] + acc[mi][ni][r] + bp[o];
            }
}

// ---------------- Flash attention: KV-split x8, LDS K(bf16)+V(fp8 swizzled), deferred PV ----------------
// qt: [b][n][c] (Q scaled by log2e/16). k3t: [m/32][c/32][32 slot][32 c] bf16 (pi-permuted).
// v8t: [m/32][c][32] fp8 e4m3, 8B-slot XOR-swizzled (conflict-free b64 reads).
// Per iter t: stage K(t+1)->K[(t+1)&1], stage V(t)->V[t&1]; QK(t); exp/cvt_pk_fp8(t);
// PV(t-1) from V[(t-1)&1]; rare O-rescale; barrier. LDS 48KB/block.
__global__ __launch_bounds__(256, 2) void attn_partial_kernel(const unsigned short* __restrict__ qt,
                                                              const unsigned short* __restrict__ k3t,
                                                              const unsigned char* __restrict__ v8t,
                                                              unsigned short* __restrict__ Opart,
                                                              float* __restrict__ ml,
                                                              int kvlen) {
    int b = blockIdx.z, split = blockIdx.y, nsplit = gridDim.y;
    int t = threadIdx.x, lane = t & 63, w = t >> 6, l15 = lane & 15, lg = lane >> 4;
    int n0 = (blockIdx.x * 4 + w) * 32;
    const size_t off = (size_t)b * N_ * C_;
    const unsigned short* Q = qt + off;
    const char* Kg = (const char*)(k3t + off);
    const char* Vg = (const char*)(v8t + off);

    __shared__ char Ktile[2][16384];
    __shared__ char Vtile[2][8192];

    s16x8 q0[8], q1[8];
    for (int kc = 0; kc < 8; ++kc) {
        q0[kc] = *(const s16x8*)(Q + (size_t)(n0 + l15) * C_ + kc * 32 + lg * 8);
        q1[kc] = *(const s16x8*)(Q + (size_t)(n0 + 16 + l15) * C_ + kc * 32 + lg * 8);
    }

    f32x4 O[2][16];
    for (int qf = 0; qf < 2; ++qf)
        for (int i = 0; i < 16; ++i) O[qf][i] = (f32x4){0.f, 0.f, 0.f, 0.f};
    float mrun[2] = {-1e30f, -1e30f};
    float lsum[2] = {0.f, 0.f};

    auto stageK = [&](int buf, int tile) {
        const char* kg = Kg + (size_t)tile * 16384;
        for (int i = 0; i < 4; ++i)
            load_lds16(kg + i * 4096 + t * 16, Ktile[buf] + i * 4096 + w * 1024);
    };
    auto stageV = [&](int buf, int tile) {
        const char* vg = Vg + (size_t)tile * 8192;
        for (int i = 0; i < 2; ++i)
            load_lds16(vg + i * 4096 + t * 16, Vtile[buf] + i * 4096 + w * 1024);
    };

    int niter = kvlen >> 5;
    int tile0 = (split * kvlen) >> 5;
    stageK(0, tile0);
    __syncthreads();   // K(0) resident

    long pap0 = 0, pap1 = 0;  // fp8 P of previous tile (A-frags)

    for (int it = 0; it < niter; ++it) {
        if (it + 1 < niter) stageK((it + 1) & 1, tile0 + it + 1);
        stageV(it & 1, tile0 + it);      // consumed next iteration

        const char* kb = Ktile[it & 1];

        // S^T = K' x Q
        f32x4 S[2][2];
        for (int qf = 0; qf < 2; ++qf)
            for (int f = 0; f < 2; ++f) S[qf][f] = (f32x4){0.f, 0.f, 0.f, 0.f};
        __builtin_amdgcn_s_setprio(1);
        for (int kc = 0; kc < 8; ++kc) {
            s16x8 k0 = *(const s16x8*)(kb + kc * 2048 + l15 * 64 + lg * 16);
            s16x8 k1 = *(const s16x8*)(kb + kc * 2048 + (16 + l15) * 64 + lg * 16);
            S[0][0] = __builtin_amdgcn_mfma_f32_16x16x32_bf16(k0, q0[kc], S[0][0], 0, 0, 0);
            S[0][1] = __builtin_amdgcn_mfma_f32_16x16x32_bf16(k1, q0[kc], S[0][1], 0, 0, 0);
            S[1][0] = __builtin_amdgcn_mfma_f32_16x16x32_bf16(k0, q1[kc], S[1][0], 0, 0, 0);
            S[1][1] = __builtin_amdgcn_mfma_f32_16x16x32_bf16(k1, q1[kc], S[1][1], 0, 0, 0);
        }
        __builtin_amdgcn_s_setprio(0);

        // per-lane local max; defer-max fast path has no cross-lane ops
        float lm0 = fmaxf(fmaxf(fmaxf(S[0][0][0], S[0][0][1]), fmaxf(S[0][0][2], S[0][0][3])),
                          fmaxf(fmaxf(S[0][1][0], S[0][1][1]), fmaxf(S[0][1][2], S[0][1][3])));
        float lm1 = fmaxf(fmaxf(fmaxf(S[1][0][0], S[1][0][1]), fmaxf(S[1][0][2], S[1][0][3])),
                          fmaxf(fmaxf(S[1][1][0], S[1][1][1]), fmaxf(S[1][1][2], S[1][1][3])));
        bool ok = (lm0 <= mrun[0] + 8.0f) && (lm1 <= mrun[1] + 8.0f);
        bool resc = !__all(ok);
        float alpha0 = 1.f, alpha1 = 1.f;
        if (resc) {
            float m0 = fmaxf(lm0, __shfl_xor(lm0, 16));
            m0 = fmaxf(m0, __shfl_xor(m0, 32));
            float nm0 = fmaxf(mrun[0], m0);
            alpha0 = __builtin_amdgcn_exp2f(mrun[0] - nm0);
            mrun[0] = nm0;
            lsum[0] *= alpha0;
            float m1 = fmaxf(lm1, __shfl_xor(lm1, 16));
            m1 = fmaxf(m1, __shfl_xor(m1, 32));
            float nm1 = fmaxf(mrun[1], m1);
            alpha1 = __builtin_amdgcn_exp2f(mrun[1] - nm1);
            mrun[1] = nm1;
            lsum[1] *= alpha1;
        }

        // exp + pack to fp8 A-frags (independent of PV below -> overlaps MFMA)
        long pac0, pac1;
        {
            float p0 = __builtin_amdgcn_exp2f(S[0][0][0] - mrun[0]);
            float p1 = __builtin_amdgcn_exp2f(S[0][0][1] - mrun[0]);
            float p2 = __builtin_amdgcn_exp2f(S[0][0][2] - mrun[0]);
            float p3 = __builtin_amdgcn_exp2f(S[0][0][3] - mrun[0]);
            float p4 = __builtin_amdgcn_exp2f(S[0][1][0] - mrun[0]);
            float p5 = __builtin_amdgcn_exp2f(S[0][1][1] - mrun[0]);
            float p6 = __builtin_amdgcn_exp2f(S[0][1][2] - mrun[0]);
            float p7 = __builtin_amdgcn_exp2f(S[0][1][3] - mrun[0]);
            lsum[0] += ((p0 + p1) + (p2 + p3)) + ((p4 + p5) + (p6 + p7));
            unsigned u0 = __builtin_amdgcn_cvt_pk_fp8_f32(p0, p1, 0, false);
            u0 = __builtin_amdgcn_cvt_pk_fp8_f32(p2, p3, u0, true);
            unsigned u1 = __builtin_amdgcn_cvt_pk_fp8_f32(p4, p5, 0, false);
            u1 = __builtin_amdgcn_cvt_pk_fp8_f32(p6, p7, u1, true);
            pac0 = (long)(((unsigned long long)u1 << 32) | u0);
        }
        {
            float p0 = __builtin_amdgcn_exp2f(S[1][0][0] - mrun[1]);
            float p1 = __builtin_amdgcn_exp2f(S[1][0][1] - mrun[1]);
            float p2 = __builtin_amdgcn_exp2f(S[1][0][2] - mrun[1]);
            float p3 = __builtin_amdgcn_exp2f(S[1][0][3] - mrun[1]);
            float p4 = __builtin_amdgcn_exp2f(S[1][1][0] - mrun[1]);
            float p5 = __builtin_amdgcn_exp2f(S[1][1][1] - mrun[1]);
            float p6 = __builtin_amdgcn_exp2f(S[1][1][2] - mrun[1]);
            float p7 = __builtin_amdgcn_exp2f(S[1][1][3] - mrun[1]);
            lsum[1] += ((p0 + p1) + (p2 + p3)) + ((p4 + p5) + (p6 + p7));
            unsigned u0 = __builtin_amdgcn_cvt_pk_fp8_f32(p0, p1, 0, false);
            u0 = __builtin_amdgcn_cvt_pk_fp8_f32(p2, p3, u0, true);
            unsigned u1 = __builtin_amdgcn_cvt_pk_fp8_f32(p4, p5, 0, false);
            u1 = __builtin_amdgcn_cvt_pk_fp8_f32(p6, p7, u1, true);
            pac1 = (long)(((unsigned long long)u1 << 32) | u0);
        }

        // PV of PREVIOUS tile (fp8 x fp8; scale m_{t-1}; O-rescale below brings to m_t)
        if (it > 0) {
            const char* vb = Vtile[(it - 1) & 1];
            __builtin_amdgcn_s_setprio(1);
            for (int cb = 0; cb < 16; ++cb) {
                int row = cb * 16 + l15;
                long vf = *(const long*)(vb + row * 32 + (((lg ^ (row >> 2)) & 3) << 3));
                O[0][cb] = __builtin_amdgcn_mfma_f32_16x16x32_fp8_fp8(pap0, vf, O[0][cb], 0, 0, 0);
                O[1][cb] = __builtin_amdgcn_mfma_f32_16x16x32_fp8_fp8(pap1, vf, O[1][cb], 0, 0, 0);
            }
            __builtin_amdgcn_s_setprio(0);
        }
        if (resc) {
            float a00 = __shfl(alpha0, lg * 4 + 0), a01 = __shfl(alpha0, lg * 4 + 1);
            float a02 = __shfl(alpha0, lg * 4 + 2), a03 = __shfl(alpha0, lg * 4 + 3);
            float a10 = __shfl(alpha1, lg * 4 + 0), a11 = __shfl(alpha1, lg * 4 + 1);
            float a12 = __shfl(alpha1, lg * 4 + 2), a13 = __shfl(alpha1, lg * 4 + 3);
            for (int i = 0; i < 16; ++i) {
                O[0][i][0] *= a00; O[0][i][1] *= a01; O[0][i][2] *= a02; O[0][i][3] *= a03;
                O[1][i][0] *= a10; O[1][i][1] *= a11; O[1][i][2] *= a12; O[1][i][3] *= a13;
            }
        }
        pap0 = pac0;
        pap1 = pac1;

        __syncthreads();   // K(t+1), V(t) resident; all waves done with K[t&1], V[(t-1)&1]
    }

    // final deferred PV (V(niter-1) resident since last barrier)
    {
        const char* vb = Vtile[(niter - 1) & 1];
        for (int cb = 0; cb < 16; ++cb) {
            int row = cb * 16 + l15;
            long vf = *(const long*)(vb + row * 32 + (((lg ^ (row >> 2)) & 3) << 3));
            O[0][cb] = __builtin_amdgcn_mfma_f32_16x16x32_fp8_fp8(pap0, vf, O[0][cb], 0, 0, 0);
            O[1][cb] = __builtin_amdgcn_mfma_f32_16x16x32_fp8_fp8(pap1, vf, O[1][cb], 0, 0, 0);
        }
    }

    for (int qf = 0; qf < 2; ++qf) {
        lsum[qf] += __shfl_xor(lsum[qf], 16);
        lsum[qf] += __shfl_xor(lsum[qf], 32);
    }

    unsigned short* Ob = Opart + (size_t)(b * nsplit + split) * N_ * C_;
    float* mlb = ml + (size_t)(b * nsplit + split) * N_ * 2;
    for (int qf = 0; qf < 2; ++qf)
        for (int cb = 0; cb < 16; ++cb)
            for (int r = 0; r < 4; ++r)
                Ob[(size_t)(n0 + qf * 16 + lg * 4 + r) * C_ + cb * 16 + l15] =
                    f2bf(qf == 0 ? O[0][cb][r] : O[1][cb][r]);
    if (lane < 16)
        for (int qf = 0; qf < 2; ++qf) {
            int n = n0 + qf * 16 + lane;
            mlb[n * 2] = mrun[qf];
            mlb[n * 2 + 1] = lsum[qf];
        }
}

// ---------------- merge partials -> ao bf16 [b][n][c] ----------------
__global__ __launch_bounds__(256) void attn_merge_kernel(const unsigned short* __restrict__ Opart,
                                                         const float* __restrict__ ml,
                                                         unsigned short* __restrict__ ao,
                                                         int nsplit) {
    int b = blockIdx.y, n = blockIdx.x, c = threadIdx.x;
    float M = -1e30f;
    for (int s = 0; s < nsplit; ++s)
        M = fmaxf(M, ml[((size_t)(b * nsplit + s) * N_ + n) * 2]);
    float L = 0.f, o = 0.f;
    for (int s = 0; s < nsplit; ++s) {
        const float* mlp = ml + ((size_t)(b * nsplit + s) * N_ + n) * 2;
        float wgt = __builtin_amdgcn_exp2f(mlp[0] - M);
        L += mlp[1] * wgt;
        o += bf2f(Opart[((size_t)(b * nsplit + s) * N_ + n) * C_ + c]) * wgt;
    }
    ao[((size_t)b * N_ + n) * C_ + c] = f2bf(o / L);
}

extern "C" void kernel_launch(void* const* d_in, const int* in_sizes, int n_in,
                              void* d_out, int out_size, void* d_ws, size_t ws_size,
                              hipStream_t stream) {
    const float* x = (const float*)d_in[0];
    const float* gamma = (const float*)d_in[1];
    const float* beta = (const float*)d_in[2];
    const float* wq = (const float*)d_in[3];
    const float* bq = (const float*)d_in[4];
    const float* wk = (const float*)d_in[5];
    const float* bk = (const float*)d_in[6];
    const float* wv = (const float*)d_in[7];
    const float* bv = (const float*)d_in[8];
    const float* wp = (const float*)d_in[9];
    const float* bp = (const float*)d_in[10];
    float* out = (float*)d_out;

    const size_t sz = (size_t)B_ * N_ * C_;
    unsigned short* hn = (unsigned short*)d_ws;  // [b][n][c]
    unsigned short* qt = hn + sz;                // [b][n][c], scaled by log2e/16
    unsigned short* kt = qt + sz;                // k3t slot layout bf16
    unsigned short* v2t = kt + sz;               // fp8 V region (sz bytes used)
    unsigned short* ao = v2t + sz;               // [b][n][c]
    unsigned short* wbf = ao + sz;               // 4 x 256 x 256 bf16
    unsigned short* Opart = wbf + 4 * 65536;     // [b][s][n][c] bf16
    int nsplit = 8;
    while (nsplit > 1 &&
           (5 * sz + 262144 + (size_t)nsplit * sz) * 2 + (size_t)nsplit * B_ * N_ * 8 + 4096 > ws_size)
        nsplit >>= 1;
    float* ml = (float*)(Opart + (size_t)nsplit * sz);   // [b][s][n][2]
    float* part = ml + (size_t)nsplit * B_ * N_ * 2;     // [256][2] GN partials

    hipLaunchKernelGGL(gn_stats_kernel, dim3(320), dim3(256), 0, stream, x, part,
                       wq, wk, wv, wp, wbf);
    hipLaunchKernelGGL(gn_apply_kernel, dim3(256), dim3(256), 0, stream, x, gamma, beta, part, hn);
    hipLaunchKernelGGL(qkv_gemm_kernel, dim3(32, 2, 6), dim3(256), 0, stream,
                       wbf, bq, bk, bv, hn, qt, kt, (unsigned char*)v2t);
    hipLaunchKernelGGL(attn_partial_kernel, dim3(32, nsplit, 2), dim3(256), 0, stream,
                       qt, kt, (const unsigned char*)v2t, Opart, ml, N_ / nsplit);
    hipLaunchKernelGGL(attn_merge_kernel, dim3(N_, 2), dim3(256), 0, stream, Opart, ml, ao, nsplit);
    hipLaunchKernelGGL(proj_gemm_kernel, dim3(64, 2, 2), dim3(256), 0, stream, wbf, bp, ao, x, out);
}

// Round 17
// 91.129 us; speedup vs baseline: 1.3370x; 1.3370x over previous
//
#include <hip/hip_runtime.h>
#include <hip/hip_bf16.h>

using f32x4 = __attribute__((ext_vector_type(4))) float;
using s16x8 = __attribute__((ext_vector_type(8))) short;
using s16x4 = __attribute__((ext_vector_type(4))) short;

#define B_ 2
#define C_ 256
#define N_ 4096
#define LOG2E 1.4426950408889634f

__device__ inline unsigned short f2bf(float f) {
    union { float f; unsigned u; } x{f};
    unsigned r = x.u + 0x7fffu + ((x.u >> 16) & 1u);
    return (unsigned short)(r >> 16);
}

__device__ inline float bf2f(unsigned short u) {
    union { unsigned u; float f; } x{(unsigned)u << 16};
    return x.f;
}

__device__ inline void load_lds16(const void* g, void* l) {
    __builtin_amdgcn_global_load_lds((const __attribute__((address_space(1))) void*)g,
                                     (__attribute__((address_space(3))) void*)l, 16, 0, 0);
}

// ---------------- GroupNorm pass 1 (blocks 0..255) + W cvt (blocks 256..319) ----------------
__global__ __launch_bounds__(256) void gn_stats_kernel(const float* __restrict__ x,
                                                       float* __restrict__ part,
                                                       const float* __restrict__ wq,
                                                       const float* __restrict__ wk,
                                                       const float* __restrict__ wv,
                                                       const float* __restrict__ wp,
                                                       unsigned short* __restrict__ wbf) {
    int blk = blockIdx.x;
    int t = threadIdx.x;
    if (blk >= 256) {
        int bi = blk - 256;
        int g = bi >> 4, chunk = bi & 15;
        const float* src = g == 0 ? wq : g == 1 ? wk : g == 2 ? wv : wp;
        int idx = chunk * 4096 + t * 16;
        for (int i = 0; i < 4; ++i) {
            float4 v = *(const float4*)(src + idx + i * 4);
            s16x4 pk;
            pk[0] = (short)f2bf(v.x); pk[1] = (short)f2bf(v.y);
            pk[2] = (short)f2bf(v.z); pk[3] = (short)f2bf(v.w);
            *(s16x4*)(wbf + g * 65536 + idx + i * 4) = pk;
        }
        return;
    }
    int qtr = blk & 3, grp = (blk >> 2) & 31, b = blk >> 7;
    const float* xb = x + ((size_t)b * C_ + grp * 8) * N_ + qtr * 1024;
    float s = 0.f, sq = 0.f;
    for (int j = 0; j < 8; ++j) {
        float4 v = *(const float4*)(xb + (size_t)j * N_ + t * 4);
        s += v.x + v.y + v.z + v.w;
        sq += v.x * v.x + v.y * v.y + v.z * v.z + v.w * v.w;
    }
    for (int off = 32; off; off >>= 1) {
        s += __shfl_down(s, off);
        sq += __shfl_down(sq, off);
    }
    __shared__ float red[2][4];
    int wid = t >> 6;
    if ((t & 63) == 0) { red[0][wid] = s; red[1][wid] = sq; }
    __syncthreads();
    if (t == 0) {
        part[blk * 2 + 0] = red[0][0] + red[0][1] + red[0][2] + red[0][3];
        part[blk * 2 + 1] = red[1][0] + red[1][1] + red[1][2] + red[1][3];
    }
}

// ---------------- GroupNorm pass 2: normalize + write bf16 [n][c] ----------------
__global__ __launch_bounds__(256) void gn_apply_kernel(const float* __restrict__ x,
                                                       const float* __restrict__ gamma,
                                                       const float* __restrict__ beta,
                                                       const float* __restrict__ part,
                                                       unsigned short* __restrict__ hn_t) {
    int blk = blockIdx.x;
    int qtr = blk & 3, grp = (blk >> 2) & 31, b = blk >> 7;
    int base = (blk & ~3) * 2;
    float S = part[base + 0] + part[base + 2] + part[base + 4] + part[base + 6];
    float Q = part[base + 1] + part[base + 3] + part[base + 5] + part[base + 7];
    float mean = S / 32768.f;
    float rstd = rsqrtf(Q / 32768.f - mean * mean + 1e-6f);

    float gm[8], bt[8];
    for (int j = 0; j < 8; ++j) {
        gm[j] = gamma[grp * 8 + j] * rstd;
        bt[j] = beta[grp * 8 + j] - mean * gm[j];
    }
    const float* xb = x + ((size_t)b * C_ + grp * 8) * N_;
    unsigned short* outp = hn_t + (size_t)b * N_ * C_ + grp * 8;
    int t = threadIdx.x;
    for (int i = 0; i < 4; ++i) {
        int n = qtr * 1024 + i * 256 + t;
        s16x8 pk;
        for (int j = 0; j < 8; ++j) {
            float v = xb[(size_t)j * N_ + n];
            pk[j] = (short)f2bf(v * gm[j] + bt[j]);
        }
        *(s16x8*)(outp + (size_t)n * C_) = pk;
    }
}

// ---------------- GEMM core: 128o x 64n tile, BK=64, dbuf, global_load_lds ----------------
__device__ inline void gemm_core(const unsigned short* __restrict__ Wg,
                                 const unsigned short* __restrict__ Bg,
                                 int o0, int n0, int t, f32x4 (&acc)[4][2],
                                 unsigned short (*At)[128 * 64], unsigned short (*Bt)[64 * 64]) {
    int lane = t & 63, w = t >> 6, l15 = lane & 15, lg = lane >> 4;
    int wo = (w >> 1) * 64, wn = (w & 1) * 32;
    int aoff[4], boff[2];
    for (int i = 0; i < 4; ++i) {
        int p = i * 4096 + t * 16;
        int y = p ^ (((p >> 7) & 7) << 4);
        aoff[i] = (o0 + (y >> 7)) * 512 + (y & 127);
    }
    for (int i = 0; i < 2; ++i) {
        int p = i * 4096 + t * 16;
        int y = p ^ (((p >> 7) & 7) << 4);
        boff[i] = (n0 + (y >> 7)) * 512 + (y & 127);
    }
    const char* Wc = (const char*)Wg;
    const char* Bc = (const char*)Bg;
    int cur = 0;
    for (int i = 0; i < 4; ++i)
        load_lds16(Wc + aoff[i], (char*)At[0] + i * 4096 + w * 1024);
    for (int i = 0; i < 2; ++i)
        load_lds16(Bc + boff[i], (char*)Bt[0] + i * 4096 + w * 1024);
    __syncthreads();
    for (int s = 0; s < 4; ++s) {
        if (s < 3) {
            int k2 = (s + 1) * 128;   // k0 * 2 bytes
            for (int i = 0; i < 4; ++i)
                load_lds16(Wc + aoff[i] + k2, (char*)At[cur ^ 1] + i * 4096 + w * 1024);
            for (int i = 0; i < 2; ++i)
                load_lds16(Bc + boff[i] + k2, (char*)Bt[cur ^ 1] + i * 4096 + w * 1024);
        }
        const char* Al = (const char*)At[cur];
        const char* Bl = (const char*)Bt[cur];
        for (int kk = 0; kk < 2; ++kk) {
            s16x8 af[4], bfv[2];
            for (int mi = 0; mi < 4; ++mi) {
                int row = wo + mi * 16 + l15;
                int lo = row * 128 + kk * 64 + lg * 16;
                af[mi] = *(const s16x8*)(Al + (lo ^ ((row & 7) << 4)));
            }
            for (int ni = 0; ni < 2; ++ni) {
                int row = wn + ni * 16 + l15;
                int lo = row * 128 + kk * 64 + lg * 16;
                bfv[ni] = *(const s16x8*)(Bl + (lo ^ ((row & 7) << 4)));
            }
            for (int mi = 0; mi < 4; ++mi)
                for (int ni = 0; ni < 2; ++ni)
                    acc[mi][ni] = __builtin_amdgcn_mfma_f32_16x16x32_bf16(af[mi], bfv[ni], acc[mi][ni], 0, 0, 0);
        }
        __syncthreads();
        cur ^= 1;
    }
}

// ---------------- fused QKV GEMM (z = b*3 + g) ----------------
__global__ __launch_bounds__(256) void qkv_gemm_kernel(const unsigned short* __restrict__ wbf,
                                                       const float* __restrict__ bq,
                                                       const float* __restrict__ bk,
                                                       const float* __restrict__ bv,
                                                       const unsigned short* __restrict__ hn,
                                                       unsigned short* __restrict__ qt,
                                                       unsigned short* __restrict__ kt,
                                                       unsigned char* __restrict__ v8t) {
    __shared__ unsigned short At[2][128 * 64];
    __shared__ unsigned short Bt[2][64 * 64];
    int g = blockIdx.z % 3, b = blockIdx.z / 3;
    const float* bias = g == 0 ? bq : g == 1 ? bk : bv;
    float scale = g == 0 ? 0.0625f * LOG2E : 1.0f;
    int o0 = blockIdx.y * 128, n0 = blockIdx.x * 64;
    int t = threadIdx.x;
    const size_t sz = (size_t)N_ * C_;

    f32x4 acc[4][2];
    for (int mi = 0; mi < 4; ++mi)
        for (int ni = 0; ni < 2; ++ni)
            acc[mi][ni] = (f32x4){0.f, 0.f, 0.f, 0.f};
    gemm_core(wbf + g * 65536, hn + b * sz, o0, n0, t, acc, At, Bt);

    int lane = t & 63, w = t >> 6, l15 = lane & 15, lg = lane >> 4;
    int wo = (w >> 1) * 64, wn = (w & 1) * 32;
    for (int mi = 0; mi < 4; ++mi)
        for (int ni = 0; ni < 2; ++ni)
            for (int r = 0; r < 4; ++r) {
                int o = o0 + wo + mi * 16 + lg * 4 + r;
                int n = n0 + wn + ni * 16 + l15;
                float val = (acc[mi][ni][r] + bias[o]) * scale;
                if (g == 0) {
                    qt[b * sz + (size_t)n * C_ + o] = f2bf(val);
                } else if (g == 1) {
                    // slot = pi^-1(n&31); element within 1024-elem chunk XOR-swizzled
                    // by (slot&7)<<3 so attn's K ds_read_b128 is bank-conflict-free.
                    int slot = ((n >> 2) & 1) * 16 + ((n >> 3) & 3) * 4 + (n & 3);
                    int e = (slot * 32 + (o & 31)) ^ ((slot & 7) << 3);
                    kt[b * sz + (size_t)(n >> 5) * 8192 + (o >> 5) * 1024 + e] = f2bf(val);
                } else {
                    unsigned pk8 = __builtin_amdgcn_cvt_pk_fp8_f32(val, 0.f, 0, false);
                    // bank-conflict-free fp8 V: 8B slot XOR-permuted by channel
                    int key = n & 31;
                    int byteoff = ((((key >> 3) ^ (o >> 2)) & 3) << 3) + (key & 7);
                    v8t[b * sz + (size_t)(n >> 5) * 8192 + o * 32 + byteoff] = (unsigned char)(pk8 & 0xff);
                }
            }
}

// ---------------- output projection GEMM + residual ----------------
__global__ __launch_bounds__(256) void proj_gemm_kernel(const unsigned short* __restrict__ wbf,
                                                        const float* __restrict__ bp,
                                                        const unsigned short* __restrict__ ao,
                                                        const float* __restrict__ x,
                                                        float* __restrict__ out) {
    __shared__ unsigned short At[2][128 * 64];
    __shared__ unsigned short Bt[2][64 * 64];
    int b = blockIdx.z;
    int o0 = blockIdx.y * 128, n0 = blockIdx.x * 64;
    int t = threadIdx.x;
    const size_t sz = (size_t)N_ * C_;

    f32x4 acc[4][2];
    for (int mi = 0; mi < 4; ++mi)
        for (int ni = 0; ni < 2; ++ni)
            acc[mi][ni] = (f32x4){0.f, 0.f, 0.f, 0.f};
    gemm_core(wbf + 3 * 65536, ao + b * sz, o0, n0, t, acc, At, Bt);

    int lane = t & 63, w = t >> 6, l15 = lane & 15, lg = lane >> 4;
    int wo = (w >> 1) * 64, wn = (w & 1) * 32;
    for (int mi = 0; mi < 4; ++mi)
        for (int ni = 0; ni < 2; ++ni)
            for (int r = 0; r < 4; ++r) {
                int o = o0 + wo + mi * 16 + lg * 4 + r;
                int n = n0 + wn + ni * 16 + l15;
                size_t idx = b * sz + (size_t)o * N_ + n;
                out[idx] = x[idx] + acc[mi][ni][r] + bp[o];
            }
}

// ---------------- Flash attention: KV-split, counted-vmcnt pipeline ----------------
// qt: [b][n][c] (Q scaled by log2e/16). k3t: [m/32][c/32][32 slot][32 c] bf16
// (pi-permuted rows, 16B-granule XOR swizzle (slot&7)<<4 for conflict-free reads).
// v8t: [m/32][c][32] fp8 e4m3, 8B-slot XOR-swizzled (conflict-free b64 reads).
// K TRIPLE-buffered (stage K(t+2) each iter), V double-buffered (stage V(t) first,
// oldest in queue). Barrier = s_waitcnt vmcnt(4) + raw s_barrier: retires V(t) and
// K(t+1) while K(t+2)'s loads stay in flight across the barrier. Tail: vmcnt(0).
__global__ __launch_bounds__(256, 2) void attn_partial_kernel(const unsigned short* __restrict__ qt,
                                                              const unsigned short* __restrict__ k3t,
                                                              const unsigned char* __restrict__ v8t,
                                                              unsigned short* __restrict__ Opart,
                                                              float* __restrict__ ml,
                                                              int kvlen) {
    int b = blockIdx.z, split = blockIdx.y, nsplit = gridDim.y;
    int t = threadIdx.x, lane = t & 63, w = t >> 6, l15 = lane & 15, lg = lane >> 4;
    int n0 = (blockIdx.x * 4 + w) * 32;
    const size_t off = (size_t)b * N_ * C_;
    const unsigned short* Q = qt + off;
    const char* Kg = (const char*)(k3t + off);
    const char* Vg = (const char*)(v8t + off);

    __shared__ char Ktile[3][16384];
    __shared__ char Vtile[2][8192];

    s16x8 q0[8], q1[8];
    for (int kc = 0; kc < 8; ++kc) {
        q0[kc] = *(const s16x8*)(Q + (size_t)(n0 + l15) * C_ + kc * 32 + lg * 8);
        q1[kc] = *(const s16x8*)(Q + (size_t)(n0 + 16 + l15) * C_ + kc * 32 + lg * 8);
    }

    f32x4 O[2][16];
    for (int qf = 0; qf < 2; ++qf)
        for (int i = 0; i < 16; ++i) O[qf][i] = (f32x4){0.f, 0.f, 0.f, 0.f};
    float mrun[2] = {-1e30f, -1e30f};
    float lsum[2] = {0.f, 0.f};

    auto stageK = [&](int buf, int tile) {
        const char* kg = Kg + (size_t)tile * 16384;
        for (int i = 0; i < 4; ++i)
            load_lds16(kg + i * 4096 + t * 16, Ktile[buf] + i * 4096 + w * 1024);
    };
    auto stageV = [&](int buf, int tile) {
        const char* vg = Vg + (size_t)tile * 8192;
        for (int i = 0; i < 2; ++i)
            load_lds16(vg + i * 4096 + t * 16, Vtile[buf] + i * 4096 + w * 1024);
    };

    int niter = kvlen >> 5;
    int tile0 = (split * kvlen) >> 5;
    stageK(0, tile0);
    if (niter > 1) stageK(1, tile0 + 1);
    asm volatile("s_waitcnt vmcnt(0)" ::: "memory");
    __builtin_amdgcn_s_barrier();
    __builtin_amdgcn_sched_barrier(0);

    long pap0 = 0, pap1 = 0;  // fp8 P of previous tile (A-frags)
    int kcur = 0;             // LDS buffer holding K(t)

    for (int it = 0; it < niter; ++it) {
        stageV(it & 1, tile0 + it);                    // V(t): oldest in queue this iter
        if (it + 2 < niter) {
            int kb2 = kcur + 2; if (kb2 >= 3) kb2 -= 3;
            stageK(kb2, tile0 + it + 2);               // K(t+2): stays in flight past barrier
        }

        const char* kb = Ktile[kcur];

        // S^T = K' x Q   (K reads XOR-deswizzled: conflict-free)
        f32x4 S[2][2];
        for (int qf = 0; qf < 2; ++qf)
            for (int f = 0; f < 2; ++f) S[qf][f] = (f32x4){0.f, 0.f, 0.f, 0.f};
        __builtin_amdgcn_s_setprio(1);
        for (int kc = 0; kc < 8; ++kc) {
            int b0 = (l15 * 64 + lg * 16) ^ ((l15 & 7) << 4);
            s16x8 k0 = *(const s16x8*)(kb + kc * 2048 + b0);
            s16x8 k1 = *(const s16x8*)(kb + kc * 2048 + 1024 + b0);
            S[0][0] = __builtin_amdgcn_mfma_f32_16x16x32_bf16(k0, q0[kc], S[0][0], 0, 0, 0);
            S[0][1] = __builtin_amdgcn_mfma_f32_16x16x32_bf16(k1, q0[kc], S[0][1], 0, 0, 0);
            S[1][0] = __builtin_amdgcn_mfma_f32_16x16x32_bf16(k0, q1[kc], S[1][0], 0, 0, 0);
            S[1][1] = __builtin_amdgcn_mfma_f32_16x16x32_bf16(k1, q1[kc], S[1][1], 0, 0, 0);
        }
        __builtin_amdgcn_s_setprio(0);

        // per-lane local max; defer-max fast path has no cross-lane ops
        float lm0 = fmaxf(fmaxf(fmaxf(S[0][0][0], S[0][0][1]), fmaxf(S[0][0][2], S[0][0][3])),
                          fmaxf(fmaxf(S[0][1][0], S[0][1][1]), fmaxf(S[0][1][2], S[0][1][3])));
        float lm1 = fmaxf(fmaxf(fmaxf(S[1][0][0], S[1][0][1]), fmaxf(S[1][0][2], S[1][0][3])),
                          fmaxf(fmaxf(S[1][1][0], S[1][1][1]), fmaxf(S[1][1][2], S[1][1][3])));
        bool ok = (lm0 <= mrun[0] + 8.0f) && (lm1 <= mrun[1] + 8.0f);
        bool resc = !__all(ok);
        float alpha0 = 1.f, alpha1 = 1.f;
        if (resc) {
            float m0 = fmaxf(lm0, __shfl_xor(lm0, 16));
            m0 = fmaxf(m0, __shfl_xor(m0, 32));
            float nm0 = fmaxf(mrun[0], m0);
            alpha0 = __builtin_amdgcn_exp2f(mrun[0] - nm0);
            mrun[0] = nm0;
            lsum[0] *= alpha0;
            float m1 = fmaxf(lm1, __shfl_xor(lm1, 16));
            m1 = fmaxf(m1, __shfl_xor(m1, 32));
            float nm1 = fmaxf(mrun[1], m1);
            alpha1 = __builtin_amdgcn_exp2f(mrun[1] - nm1);
            mrun[1] = nm1;
            lsum[1] *= alpha1;
        }

        // exp + pack to fp8 A-frags (independent of PV below -> overlaps MFMA)
        long pac0, pac1;
        {
            float p0 = __builtin_amdgcn_exp2f(S[0][0][0] - mrun[0]);
            float p1 = __builtin_amdgcn_exp2f(S[0][0][1] - mrun[0]);
            float p2 = __builtin_amdgcn_exp2f(S[0][0][2] - mrun[0]);
            float p3 = __builtin_amdgcn_exp2f(S[0][0][3] - mrun[0]);
            float p4 = __builtin_amdgcn_exp2f(S[0][1][0] - mrun[0]);
            float p5 = __builtin_amdgcn_exp2f(S[0][1][1] - mrun[0]);
            float p6 = __builtin_amdgcn_exp2f(S[0][1][2] - mrun[0]);
            float p7 = __builtin_amdgcn_exp2f(S[0][1][3] - mrun[0]);
            lsum[0] += ((p0 + p1) + (p2 + p3)) + ((p4 + p5) + (p6 + p7));
            unsigned u0 = __builtin_amdgcn_cvt_pk_fp8_f32(p0, p1, 0, false);
            u0 = __builtin_amdgcn_cvt_pk_fp8_f32(p2, p3, u0, true);
            unsigned u1 = __builtin_amdgcn_cvt_pk_fp8_f32(p4, p5, 0, false);
            u1 = __builtin_amdgcn_cvt_pk_fp8_f32(p6, p7, u1, true);
            pac0 = (long)(((unsigned long long)u1 << 32) | u0);
        }
        {
            float p0 = __builtin_amdgcn_exp2f(S[1][0][0] - mrun[1]);
            float p1 = __builtin_amdgcn_exp2f(S[1][0][1] - mrun[1]);
            float p2 = __builtin_amdgcn_exp2f(S[1][0][2] - mrun[1]);
            float p3 = __builtin_amdgcn_exp2f(S[1][0][3] - mrun[1]);
            float p4 = __builtin_amdgcn_exp2f(S[1][1][0] - mrun[1]);
            float p5 = __builtin_amdgcn_exp2f(S[1][1][1] - mrun[1]);
            float p6 = __builtin_amdgcn_exp2f(S[1][1][2] - mrun[1]);
            float p7 = __builtin_amdgcn_exp2f(S[1][1][3] - mrun[1]);
            lsum[1] += ((p0 + p1) + (p2 + p3)) + ((p4 + p5) + (p6 + p7));
            unsigned u0 = __builtin_amdgcn_cvt_pk_fp8_f32(p0, p1, 0, false);
            u0 = __builtin_amdgcn_cvt_pk_fp8_f32(p2, p3, u0, true);
            unsigned u1 = __builtin_amdgcn_cvt_pk_fp8_f32(p4, p5, 0, false);
            u1 = __builtin_amdgcn_cvt_pk_fp8_f32(p6, p7, u1, true);
            pac1 = (long)(((unsigned long long)u1 << 32) | u0);
        }

        // PV of PREVIOUS tile (fp8 x fp8; scale m_{t-1}; O-rescale below brings to m_t)
        if (it > 0) {
            const char* vb = Vtile[(it - 1) & 1];
            __builtin_amdgcn_s_setprio(1);
            for (int cb = 0; cb < 16; ++cb) {
                int row = cb * 16 + l15;
                long vf = *(const long*)(vb + row * 32 + (((lg ^ (row >> 2)) & 3) << 3));
                O[0][cb] = __builtin_amdgcn_mfma_f32_16x16x32_fp8_fp8(pap0, vf, O[0][cb], 0, 0, 0);
                O[1][cb] = __builtin_amdgcn_mfma_f32_16x16x32_fp8_fp8(pap1, vf, O[1][cb], 0, 0, 0);
            }
            __builtin_amdgcn_s_setprio(0);
        }
        if (resc) {
            float a00 = __shfl(alpha0, lg * 4 + 0), a01 = __shfl(alpha0, lg * 4 + 1);
            float a02 = __shfl(alpha0, lg * 4 + 2), a03 = __shfl(alpha0, lg * 4 + 3);
            float a10 = __shfl(alpha1, lg * 4 + 0), a11 = __shfl(alpha1, lg * 4 + 1);
            float a12 = __shfl(alpha1, lg * 4 + 2), a13 = __shfl(alpha1, lg * 4 + 3);
            for (int i = 0; i < 16; ++i) {
                O[0][i][0] *= a00; O[0][i][1] *= a01; O[0][i][2] *= a02; O[0][i][3] *= a03;
                O[1][i][0] *= a10; O[1][i][1] *= a11; O[1][i][2] *= a12; O[1][i][3] *= a13;
            }
        }
        pap0 = pac0;
        pap1 = pac1;

        // counted-vmcnt barrier: retire V(t) (+ older) but keep K(t+2) in flight
        __builtin_amdgcn_sched_barrier(0);
        if (it + 2 < niter)
            asm volatile("s_waitcnt vmcnt(4)" ::: "memory");
        else
            asm volatile("s_waitcnt vmcnt(0)" ::: "memory");
        __builtin_amdgcn_s_barrier();
        __builtin_amdgcn_sched_barrier(0);
        kcur = kcur + 1; if (kcur >= 3) kcur -= 3;
    }

    // final deferred PV (last barrier was vmcnt(0): V(niter-1) resident)
    {
        const char* vb = Vtile[(niter - 1) & 1];
        for (int cb = 0; cb < 16; ++cb) {
            int row = cb * 16 + l15;
            long vf = *(const long*)(vb + row * 32 + (((lg ^ (row >> 2)) & 3) << 3));
            O[0][cb] = __builtin_amdgcn_mfma_f32_16x16x32_fp8_fp8(pap0, vf, O[0][cb], 0, 0, 0);
            O[1][cb] = __builtin_amdgcn_mfma_f32_16x16x32_fp8_fp8(pap1, vf, O[1][cb], 0, 0, 0);
        }
    }

    for (int qf = 0; qf < 2; ++qf) {
        lsum[qf] += __shfl_xor(lsum[qf], 16);
        lsum[qf] += __shfl_xor(lsum[qf], 32);
    }

    unsigned short* Ob = Opart + (size_t)(b * nsplit + split) * N_ * C_;
    float* mlb = ml + (size_t)(b * nsplit + split) * N_ * 2;
    for (int qf = 0; qf < 2; ++qf)
        for (int cb = 0; cb < 16; ++cb)
            for (int r = 0; r < 4; ++r)
                Ob[(size_t)(n0 + qf * 16 + lg * 4 + r) * C_ + cb * 16 + l15] =
                    f2bf(qf == 0 ? O[0][cb][r] : O[1][cb][r]);
    if (lane < 16)
        for (int qf = 0; qf < 2; ++qf) {
            int n = n0 + qf * 16 + lane;
            mlb[n * 2] = mrun[qf];
            mlb[n * 2 + 1] = lsum[qf];
        }
}

// ---------------- merge partials -> ao bf16 [b][n][c] ----------------
__global__ __launch_bounds__(256) void attn_merge_kernel(const unsigned short* __restrict__ Opart,
                                                         const float* __restrict__ ml,
                                                         unsigned short* __restrict__ ao,
                                                         int nsplit) {
    int b = blockIdx.y, n = blockIdx.x, c = threadIdx.x;
    float M = -1e30f;
    for (int s = 0; s < nsplit; ++s)
        M = fmaxf(M, ml[((size_t)(b * nsplit + s) * N_ + n) * 2]);
    float L = 0.f, o = 0.f;
    for (int s = 0; s < nsplit; ++s) {
        const float* mlp = ml + ((size_t)(b * nsplit + s) * N_ + n) * 2;
        float wgt = __builtin_amdgcn_exp2f(mlp[0] - M);
        L += mlp[1] * wgt;
        o += bf2f(Opart[((size_t)(b * nsplit + s) * N_ + n) * C_ + c]) * wgt;
    }
    ao[((size_t)b * N_ + n) * C_ + c] = f2bf(o / L);
}

extern "C" void kernel_launch(void* const* d_in, const int* in_sizes, int n_in,
                              void* d_out, int out_size, void* d_ws, size_t ws_size,
                              hipStream_t stream) {
    const float* x = (const float*)d_in[0];
    const float* gamma = (const float*)d_in[1];
    const float* beta = (const float*)d_in[2];
    const float* wq = (const float*)d_in[3];
    const float* bq = (const float*)d_in[4];
    const float* wk = (const float*)d_in[5];
    const float* bk = (const float*)d_in[6];
    const float* wv = (const float*)d_in[7];
    const float* bv = (const float*)d_in[8];
    const float* wp = (const float*)d_in[9];
    const float* bp = (const float*)d_in[10];
    float* out = (float*)d_out;

    const size_t sz = (size_t)B_ * N_ * C_;
    unsigned short* hn = (unsigned short*)d_ws;  // [b][n][c]
    unsigned short* qt = hn + sz;                // [b][n][c], scaled by log2e/16
    unsigned short* kt = qt + sz;                // k3t slot layout bf16 (swizzled)
    unsigned short* v2t = kt + sz;               // fp8 V region (sz bytes used)
    unsigned short* ao = v2t + sz;               // [b][n][c]
    unsigned short* wbf = ao + sz;               // 4 x 256 x 256 bf16
    unsigned short* Opart = wbf + 4 * 65536;     // [b][s][n][c] bf16
    int nsplit = 8;
    while (nsplit > 1 &&
           (5 * sz + 262144 + (size_t)nsplit * sz) * 2 + (size_t)nsplit * B_ * N_ * 8 + 4096 > ws_size)
        nsplit >>= 1;
    float* ml = (float*)(Opart + (size_t)nsplit * sz);   // [b][s][n][2]
    float* part = ml + (size_t)nsplit * B_ * N_ * 2;     // [256][2] GN partials

    hipLaunchKernelGGL(gn_stats_kernel, dim3(320), dim3(256), 0, stream, x, part,
                       wq, wk, wv, wp, wbf);
    hipLaunchKernelGGL(gn_apply_kernel, dim3(256), dim3(256), 0, stream, x, gamma, beta, part, hn);
    hipLaunchKernelGGL(qkv_gemm_kernel, dim3(64, 2, 6), dim3(256), 0, stream,
                       wbf, bq, bk, bv, hn, qt, kt, (unsigned char*)v2t);
    hipLaunchKernelGGL(attn_partial_kernel, dim3(32, nsplit, 2), dim3(256), 0, stream,
                       qt, kt, (const unsigned char*)v2t, Opart, ml, N_ / nsplit);
    hipLaunchKernelGGL(attn_merge_kernel, dim3(N_, 2), dim3(256), 0, stream, Opart, ml, ao, nsplit);
    hipLaunchKernelGGL(proj_gemm_kernel, dim3(64, 2, 2), dim3(256), 0, stream, wbf, bp, ao, x, out);
}

// Round 18
// 76.336 us; speedup vs baseline: 1.5961x; 1.1938x over previous
//
#include <hip/hip_runtime.h>
#include <hip/hip_bf16.h>

using f32x4 = __attribute__((ext_vector_type(4))) float;
using s16x8 = __attribute__((ext_vector_type(8))) short;
using s16x4 = __attribute__((ext_vector_type(4))) short;

#define B_ 2
#define C_ 256
#define N_ 4096
#define LOG2E 1.4426950408889634f

__device__ inline unsigned short f2bf(float f) {
    union { float f; unsigned u; } x{f};
    unsigned r = x.u + 0x7fffu + ((x.u >> 16) & 1u);
    return (unsigned short)(r >> 16);
}

__device__ inline float bf2f(unsigned short u) {
    union { unsigned u; float f; } x{(unsigned)u << 16};
    return x.f;
}

__device__ inline void load_lds16(const void* g, void* l) {
    __builtin_amdgcn_global_load_lds((const __attribute__((address_space(1))) void*)g,
                                     (__attribute__((address_space(3))) void*)l, 16, 0, 0);
}

// ---------------- GroupNorm pass 1 (blocks 0..255) + W cvt (blocks 256..319) ----------------
__global__ __launch_bounds__(256) void gn_stats_kernel(const float* __restrict__ x,
                                                       float* __restrict__ part,
                                                       const float* __restrict__ wq,
                                                       const float* __restrict__ wk,
                                                       const float* __restrict__ wv,
                                                       const float* __restrict__ wp,
                                                       unsigned short* __restrict__ wbf) {
    int blk = blockIdx.x;
    int t = threadIdx.x;
    if (blk >= 256) {
        int bi = blk - 256;
        int g = bi >> 4, chunk = bi & 15;
        const float* src = g == 0 ? wq : g == 1 ? wk : g == 2 ? wv : wp;
        int idx = chunk * 4096 + t * 16;
        for (int i = 0; i < 4; ++i) {
            float4 v = *(const float4*)(src + idx + i * 4);
            s16x4 pk;
            pk[0] = (short)f2bf(v.x); pk[1] = (short)f2bf(v.y);
            pk[2] = (short)f2bf(v.z); pk[3] = (short)f2bf(v.w);
            *(s16x4*)(wbf + g * 65536 + idx + i * 4) = pk;
        }
        return;
    }
    int qtr = blk & 3, grp = (blk >> 2) & 31, b = blk >> 7;
    const float* xb = x + ((size_t)b * C_ + grp * 8) * N_ + qtr * 1024;
    float s = 0.f, sq = 0.f;
    for (int j = 0; j < 8; ++j) {
        float4 v = *(const float4*)(xb + (size_t)j * N_ + t * 4);
        s += v.x + v.y + v.z + v.w;
        sq += v.x * v.x + v.y * v.y + v.z * v.z + v.w * v.w;
    }
    for (int off = 32; off; off >>= 1) {
        s += __shfl_down(s, off);
        sq += __shfl_down(sq, off);
    }
    __shared__ float red[2][4];
    int wid = t >> 6;
    if ((t & 63) == 0) { red[0][wid] = s; red[1][wid] = sq; }
    __syncthreads();
    if (t == 0) {
        part[blk * 2 + 0] = red[0][0] + red[0][1] + red[0][2] + red[0][3];
        part[blk * 2 + 1] = red[1][0] + red[1][1] + red[1][2] + red[1][3];
    }
}

// ---------------- GroupNorm pass 2: normalize + write bf16 [n][c] ----------------
__global__ __launch_bounds__(256) void gn_apply_kernel(const float* __restrict__ x,
                                                       const float* __restrict__ gamma,
                                                       const float* __restrict__ beta,
                                                       const float* __restrict__ part,
                                                       unsigned short* __restrict__ hn_t) {
    int blk = blockIdx.x;
    int qtr = blk & 3, grp = (blk >> 2) & 31, b = blk >> 7;
    int base = (blk & ~3) * 2;
    float S = part[base + 0] + part[base + 2] + part[base + 4] + part[base + 6];
    float Q = part[base + 1] + part[base + 3] + part[base + 5] + part[base + 7];
    float mean = S / 32768.f;
    float rstd = rsqrtf(Q / 32768.f - mean * mean + 1e-6f);

    float gm[8], bt[8];
    for (int j = 0; j < 8; ++j) {
        gm[j] = gamma[grp * 8 + j] * rstd;
        bt[j] = beta[grp * 8 + j] - mean * gm[j];
    }
    const float* xb = x + ((size_t)b * C_ + grp * 8) * N_;
    unsigned short* outp = hn_t + (size_t)b * N_ * C_ + grp * 8;
    int t = threadIdx.x;
    for (int i = 0; i < 4; ++i) {
        int n = qtr * 1024 + i * 256 + t;
        s16x8 pk;
        for (int j = 0; j < 8; ++j) {
            float v = xb[(size_t)j * N_ + n];
            pk[j] = (short)f2bf(v * gm[j] + bt[j]);
        }
        *(s16x8*)(outp + (size_t)n * C_) = pk;
    }
}

// ---------------- GEMM core: 128o x 64n tile, BK=64, dbuf, global_load_lds ----------------
__device__ inline void gemm_core(const unsigned short* __restrict__ Wg,
                                 const unsigned short* __restrict__ Bg,
                                 int o0, int n0, int t, f32x4 (&acc)[4][2],
                                 unsigned short (*At)[128 * 64], unsigned short (*Bt)[64 * 64]) {
    int lane = t & 63, w = t >> 6, l15 = lane & 15, lg = lane >> 4;
    int wo = (w >> 1) * 64, wn = (w & 1) * 32;
    int aoff[4], boff[2];
    for (int i = 0; i < 4; ++i) {
        int p = i * 4096 + t * 16;
        int y = p ^ (((p >> 7) & 7) << 4);
        aoff[i] = (o0 + (y >> 7)) * 512 + (y & 127);
    }
    for (int i = 0; i < 2; ++i) {
        int p = i * 4096 + t * 16;
        int y = p ^ (((p >> 7) & 7) << 4);
        boff[i] = (n0 + (y >> 7)) * 512 + (y & 127);
    }
    const char* Wc = (const char*)Wg;
    const char* Bc = (const char*)Bg;
    int cur = 0;
    for (int i = 0; i < 4; ++i)
        load_lds16(Wc + aoff[i], (char*)At[0] + i * 4096 + w * 1024);
    for (int i = 0; i < 2; ++i)
        load_lds16(Bc + boff[i], (char*)Bt[0] + i * 4096 + w * 1024);
    __syncthreads();
    for (int s = 0; s < 4; ++s) {
        if (s < 3) {
            int k2 = (s + 1) * 128;   // k0 * 2 bytes
            for (int i = 0; i < 4; ++i)
                load_lds16(Wc + aoff[i] + k2, (char*)At[cur ^ 1] + i * 4096 + w * 1024);
            for (int i = 0; i < 2; ++i)
                load_lds16(Bc + boff[i] + k2, (char*)Bt[cur ^ 1] + i * 4096 + w * 1024);
        }
        const char* Al = (const char*)At[cur];
        const char* Bl = (const char*)Bt[cur];
        for (int kk = 0; kk < 2; ++kk) {
            s16x8 af[4], bfv[2];
            for (int mi = 0; mi < 4; ++mi) {
                int row = wo + mi * 16 + l15;
                int lo = row * 128 + kk * 64 + lg * 16;
                af[mi] = *(const s16x8*)(Al + (lo ^ ((row & 7) << 4)));
            }
            for (int ni = 0; ni < 2; ++ni) {
                int row = wn + ni * 16 + l15;
                int lo = row * 128 + kk * 64 + lg * 16;
                bfv[ni] = *(const s16x8*)(Bl + (lo ^ ((row & 7) << 4)));
            }
            for (int mi = 0; mi < 4; ++mi)
                for (int ni = 0; ni < 2; ++ni)
                    acc[mi][ni] = __builtin_amdgcn_mfma_f32_16x16x32_bf16(af[mi], bfv[ni], acc[mi][ni], 0, 0, 0);
        }
        __syncthreads();
        cur ^= 1;
    }
}

// ---------------- fused QKV GEMM (z = b*3 + g) ----------------
__global__ __launch_bounds__(256) void qkv_gemm_kernel(const unsigned short* __restrict__ wbf,
                                                       const float* __restrict__ bq,
                                                       const float* __restrict__ bk,
                                                       const float* __restrict__ bv,
                                                       const unsigned short* __restrict__ hn,
                                                       unsigned short* __restrict__ qt,
                                                       unsigned short* __restrict__ kt,
                                                       unsigned char* __restrict__ v8t) {
    __shared__ unsigned short At[2][128 * 64];
    __shared__ unsigned short Bt[2][64 * 64];
    int g = blockIdx.z % 3, b = blockIdx.z / 3;
    const float* bias = g == 0 ? bq : g == 1 ? bk : bv;
    float scale = g == 0 ? 0.0625f * LOG2E : 1.0f;
    int o0 = blockIdx.y * 128, n0 = blockIdx.x * 64;
    int t = threadIdx.x;
    const size_t sz = (size_t)N_ * C_;

    f32x4 acc[4][2];
    for (int mi = 0; mi < 4; ++mi)
        for (int ni = 0; ni < 2; ++ni)
            acc[mi][ni] = (f32x4){0.f, 0.f, 0.f, 0.f};
    gemm_core(wbf + g * 65536, hn + b * sz, o0, n0, t, acc, At, Bt);

    int lane = t & 63, w = t >> 6, l15 = lane & 15, lg = lane >> 4;
    int wo = (w >> 1) * 64, wn = (w & 1) * 32;
    for (int mi = 0; mi < 4; ++mi)
        for (int ni = 0; ni < 2; ++ni) {
            int obase = o0 + wo + mi * 16 + lg * 4;
            int n = n0 + wn + ni * 16 + l15;
            float v0 = (acc[mi][ni][0] + bias[obase + 0]) * scale;
            float v1 = (acc[mi][ni][1] + bias[obase + 1]) * scale;
            float v2 = (acc[mi][ni][2] + bias[obase + 2]) * scale;
            float v3 = (acc[mi][ni][3] + bias[obase + 3]) * scale;
            if (g == 0) {
                s16x4 pk;
                pk[0] = (short)f2bf(v0); pk[1] = (short)f2bf(v1);
                pk[2] = (short)f2bf(v2); pk[3] = (short)f2bf(v3);
                *(s16x4*)(qt + b * sz + (size_t)n * C_ + obase) = pk;
            } else if (g == 1) {
                // slot = pi^-1(n&31); element XOR-swizzled by (slot&7)<<3
                int slot = ((n >> 2) & 1) * 16 + ((n >> 3) & 3) * 4 + (n & 3);
                int e0 = (slot * 32 + (obase & 31)) ^ ((slot & 7) << 3);
                s16x4 pk;
                pk[0] = (short)f2bf(v0); pk[1] = (short)f2bf(v1);
                pk[2] = (short)f2bf(v2); pk[3] = (short)f2bf(v3);
                *(s16x4*)(kt + b * sz + (size_t)(n >> 5) * 8192 + (obase >> 5) * 1024 + e0) = pk;
            } else {
                float vv[4] = {v0, v1, v2, v3};
                for (int r = 0; r < 4; ++r) {
                    int o = obase + r;
                    unsigned pk8 = __builtin_amdgcn_cvt_pk_fp8_f32(vv[r], 0.f, 0, false);
                    int key = n & 31;
                    int byteoff = ((((key >> 3) ^ (o >> 2)) & 3) << 3) + (key & 7);
                    v8t[b * sz + (size_t)(n >> 5) * 8192 + o * 32 + byteoff] = (unsigned char)(pk8 & 0xff);
                }
            }
        }
}

// ---------------- output projection GEMM + residual ----------------
__global__ __launch_bounds__(256) void proj_gemm_kernel(const unsigned short* __restrict__ wbf,
                                                        const float* __restrict__ bp,
                                                        const unsigned short* __restrict__ ao,
                                                        const float* __restrict__ x,
                                                        float* __restrict__ out) {
    __shared__ unsigned short At[2][128 * 64];
    __shared__ unsigned short Bt[2][64 * 64];
    int b = blockIdx.z;
    int o0 = blockIdx.y * 128, n0 = blockIdx.x * 64;
    int t = threadIdx.x;
    const size_t sz = (size_t)N_ * C_;

    f32x4 acc[4][2];
    for (int mi = 0; mi < 4; ++mi)
        for (int ni = 0; ni < 2; ++ni)
            acc[mi][ni] = (f32x4){0.f, 0.f, 0.f, 0.f};
    gemm_core(wbf + 3 * 65536, ao + b * sz, o0, n0, t, acc, At, Bt);

    int lane = t & 63, w = t >> 6, l15 = lane & 15, lg = lane >> 4;
    int wo = (w >> 1) * 64, wn = (w & 1) * 32;
    for (int mi = 0; mi < 4; ++mi)
        for (int ni = 0; ni < 2; ++ni)
            for (int r = 0; r < 4; ++r) {
                int o = o0 + wo + mi * 16 + lg * 4 + r;
                int n = n0 + wn + ni * 16 + l15;
                size_t idx = b * sz + (size_t)o * N_ + n;
                out[idx] = x[idx] + acc[mi][ni][r] + bp[o];
            }
}

// ---------------- Flash attention: KV-split, counted-vmcnt pipeline ----------------
// qt: [b][n][c] (Q scaled by log2e/16). k3t: [m/32][c/32][32 slot][32 c] bf16
// (pi-permuted rows, 16B-granule XOR swizzle). v8t: [m/32][c][32] fp8 e4m3,
// 8B-slot XOR-swizzled. K triple-buffered (stage K(t+2)), V double-buffered
// (stage V(t) first, oldest in queue). Barrier = s_waitcnt vmcnt(4) + s_barrier.
__global__ __launch_bounds__(256, 2) void attn_partial_kernel(const unsigned short* __restrict__ qt,
                                                              const unsigned short* __restrict__ k3t,
                                                              const unsigned char* __restrict__ v8t,
                                                              unsigned short* __restrict__ Opart,
                                                              float* __restrict__ ml,
                                                              int kvlen) {
    int b = blockIdx.z, split = blockIdx.y, nsplit = gridDim.y;
    int t = threadIdx.x, lane = t & 63, w = t >> 6, l15 = lane & 15, lg = lane >> 4;
    int n0 = (blockIdx.x * 4 + w) * 32;
    const size_t off = (size_t)b * N_ * C_;
    const unsigned short* Q = qt + off;
    const char* Kg = (const char*)(k3t + off);
    const char* Vg = (const char*)(v8t + off);

    __shared__ char Ktile[3][16384];
    __shared__ char Vtile[2][8192];

    s16x8 q0[8], q1[8];
    for (int kc = 0; kc < 8; ++kc) {
        q0[kc] = *(const s16x8*)(Q + (size_t)(n0 + l15) * C_ + kc * 32 + lg * 8);
        q1[kc] = *(const s16x8*)(Q + (size_t)(n0 + 16 + l15) * C_ + kc * 32 + lg * 8);
    }

    f32x4 O[2][16];
    for (int qf = 0; qf < 2; ++qf)
        for (int i = 0; i < 16; ++i) O[qf][i] = (f32x4){0.f, 0.f, 0.f, 0.f};
    float mrun[2] = {-1e30f, -1e30f};
    float lsum[2] = {0.f, 0.f};

    auto stageK = [&](int buf, int tile) {
        const char* kg = Kg + (size_t)tile * 16384;
        for (int i = 0; i < 4; ++i)
            load_lds16(kg + i * 4096 + t * 16, Ktile[buf] + i * 4096 + w * 1024);
    };
    auto stageV = [&](int buf, int tile) {
        const char* vg = Vg + (size_t)tile * 8192;
        for (int i = 0; i < 2; ++i)
            load_lds16(vg + i * 4096 + t * 16, Vtile[buf] + i * 4096 + w * 1024);
    };

    int niter = kvlen >> 5;
    int tile0 = (split * kvlen) >> 5;
    stageK(0, tile0);
    if (niter > 1) stageK(1, tile0 + 1);
    asm volatile("s_waitcnt vmcnt(0)" ::: "memory");
    __builtin_amdgcn_s_barrier();
    __builtin_amdgcn_sched_barrier(0);

    long pap0 = 0, pap1 = 0;  // fp8 P of previous tile (A-frags)
    int kcur = 0;             // LDS buffer holding K(t)

    for (int it = 0; it < niter; ++it) {
        stageV(it & 1, tile0 + it);                    // V(t): oldest in queue this iter
        if (it + 2 < niter) {
            int kb2 = kcur + 2; if (kb2 >= 3) kb2 -= 3;
            stageK(kb2, tile0 + it + 2);               // K(t+2): stays in flight past barrier
        }

        const char* kb = Ktile[kcur];

        // S^T = K' x Q   (K reads XOR-deswizzled)
        f32x4 S[2][2];
        for (int qf = 0; qf < 2; ++qf)
            for (int f = 0; f < 2; ++f) S[qf][f] = (f32x4){0.f, 0.f, 0.f, 0.f};
        __builtin_amdgcn_s_setprio(1);
        for (int kc = 0; kc < 8; ++kc) {
            int b0 = (l15 * 64 + lg * 16) ^ ((l15 & 7) << 4);
            s16x8 k0 = *(const s16x8*)(kb + kc * 2048 + b0);
            s16x8 k1 = *(const s16x8*)(kb + kc * 2048 + 1024 + b0);
            S[0][0] = __builtin_amdgcn_mfma_f32_16x16x32_bf16(k0, q0[kc], S[0][0], 0, 0, 0);
            S[0][1] = __builtin_amdgcn_mfma_f32_16x16x32_bf16(k1, q0[kc], S[0][1], 0, 0, 0);
            S[1][0] = __builtin_amdgcn_mfma_f32_16x16x32_bf16(k0, q1[kc], S[1][0], 0, 0, 0);
            S[1][1] = __builtin_amdgcn_mfma_f32_16x16x32_bf16(k1, q1[kc], S[1][1], 0, 0, 0);
        }
        __builtin_amdgcn_s_setprio(0);

        // per-lane local max; defer-max fast path has no cross-lane ops
        float lm0 = fmaxf(fmaxf(fmaxf(S[0][0][0], S[0][0][1]), fmaxf(S[0][0][2], S[0][0][3])),
                          fmaxf(fmaxf(S[0][1][0], S[0][1][1]), fmaxf(S[0][1][2], S[0][1][3])));
        float lm1 = fmaxf(fmaxf(fmaxf(S[1][0][0], S[1][0][1]), fmaxf(S[1][0][2], S[1][0][3])),
                          fmaxf(fmaxf(S[1][1][0], S[1][1][1]), fmaxf(S[1][1][2], S[1][1][3])));
        bool ok = (lm0 <= mrun[0] + 8.0f) && (lm1 <= mrun[1] + 8.0f);
        bool resc = !__all(ok);
        float alpha0 = 1.f, alpha1 = 1.f;
        if (resc) {
            float m0 = fmaxf(lm0, __shfl_xor(lm0, 16));
            m0 = fmaxf(m0, __shfl_xor(m0, 32));
            float nm0 = fmaxf(mrun[0], m0);
            alpha0 = __builtin_amdgcn_exp2f(mrun[0] - nm0);
            mrun[0] = nm0;
            lsum[0] *= alpha0;
            float m1 = fmaxf(lm1, __shfl_xor(lm1, 16));
            m1 = fmaxf(m1, __shfl_xor(m1, 32));
            float nm1 = fmaxf(mrun[1], m1);
            alpha1 = __builtin_amdgcn_exp2f(mrun[1] - nm1);
            mrun[1] = nm1;
            lsum[1] *= alpha1;
        }

        // exp + pack to fp8 A-frags (independent of PV below -> overlaps MFMA)
        long pac0, pac1;
        {
            float p0 = __builtin_amdgcn_exp2f(S[0][0][0] - mrun[0]);
            float p1 = __builtin_amdgcn_exp2f(S[0][0][1] - mrun[0]);
            float p2 = __builtin_amdgcn_exp2f(S[0][0][2] - mrun[0]);
            float p3 = __builtin_amdgcn_exp2f(S[0][0][3] - mrun[0]);
            float p4 = __builtin_amdgcn_exp2f(S[0][1][0] - mrun[0]);
            float p5 = __builtin_amdgcn_exp2f(S[0][1][1] - mrun[0]);
            float p6 = __builtin_amdgcn_exp2f(S[0][1][2] - mrun[0]);
            float p7 = __builtin_amdgcn_exp2f(S[0][1][3] - mrun[0]);
            lsum[0] += ((p0 + p1) + (p2 + p3)) + ((p4 + p5) + (p6 + p7));
            unsigned u0 = __builtin_amdgcn_cvt_pk_fp8_f32(p0, p1, 0, false);
            u0 = __builtin_amdgcn_cvt_pk_fp8_f32(p2, p3, u0, true);
            unsigned u1 = __builtin_amdgcn_cvt_pk_fp8_f32(p4, p5, 0, false);
            u1 = __builtin_amdgcn_cvt_pk_fp8_f32(p6, p7, u1, true);
            pac0 = (long)(((unsigned long long)u1 << 32) | u0);
        }
        {
            float p0 = __builtin_amdgcn_exp2f(S[1][0][0] - mrun[1]);
            float p1 = __builtin_amdgcn_exp2f(S[1][0][1] - mrun[1]);
            float p2 = __builtin_amdgcn_exp2f(S[1][0][2] - mrun[1]);
            float p3 = __builtin_amdgcn_exp2f(S[1][0][3] - mrun[1]);
            float p4 = __builtin_amdgcn_exp2f(S[1][1][0] - mrun[1]);
            float p5 = __builtin_amdgcn_exp2f(S[1][1][1] - mrun[1]);
            float p6 = __builtin_amdgcn_exp2f(S[1][1][2] - mrun[1]);
            float p7 = __builtin_amdgcn_exp2f(S[1][1][3] - mrun[1]);
            lsum[1] += ((p0 + p1) + (p2 + p3)) + ((p4 + p5) + (p6 + p7));
            unsigned u0 = __builtin_amdgcn_cvt_pk_fp8_f32(p0, p1, 0, false);
            u0 = __builtin_amdgcn_cvt_pk_fp8_f32(p2, p3, u0, true);
            unsigned u1 = __builtin_amdgcn_cvt_pk_fp8_f32(p4, p5, 0, false);
            u1 = __builtin_amdgcn_cvt_pk_fp8_f32(p6, p7, u1, true);
            pac1 = (long)(((unsigned long long)u1 << 32) | u0);
        }

        // PV of PREVIOUS tile (fp8 x fp8; scale m_{t-1}; O-rescale below brings to m_t)
        if (it > 0) {
            const char* vb = Vtile[(it - 1) & 1];
            __builtin_amdgcn_s_setprio(1);
            for (int cb = 0; cb < 16; ++cb) {
                int row = cb * 16 + l15;
                long vf = *(const long*)(vb + row * 32 + (((lg ^ (row >> 2)) & 3) << 3));
                O[0][cb] = __builtin_amdgcn_mfma_f32_16x16x32_fp8_fp8(pap0, vf, O[0][cb], 0, 0, 0);
                O[1][cb] = __builtin_amdgcn_mfma_f32_16x16x32_fp8_fp8(pap1, vf, O[1][cb], 0, 0, 0);
            }
            __builtin_amdgcn_s_setprio(0);
        }
        if (resc) {
            float a00 = __shfl(alpha0, lg * 4 + 0), a01 = __shfl(alpha0, lg * 4 + 1);
            float a02 = __shfl(alpha0, lg * 4 + 2), a03 = __shfl(alpha0, lg * 4 + 3);
            float a10 = __shfl(alpha1, lg * 4 + 0), a11 = __shfl(alpha1, lg * 4 + 1);
            float a12 = __shfl(alpha1, lg * 4 + 2), a13 = __shfl(alpha1, lg * 4 + 3);
            for (int i = 0; i < 16; ++i) {
                O[0][i][0] *= a00; O[0][i][1] *= a01; O[0][i][2] *= a02; O[0][i][3] *= a03;
                O[1][i][0] *= a10; O[1][i][1] *= a11; O[1][i][2] *= a12; O[1][i][3] *= a13;
            }
        }
        pap0 = pac0;
        pap1 = pac1;

        // counted-vmcnt barrier: retire V(t) (+ older) but keep K(t+2) in flight
        __builtin_amdgcn_sched_barrier(0);
        if (it + 2 < niter)
            asm volatile("s_waitcnt vmcnt(4)" ::: "memory");
        else
            asm volatile("s_waitcnt vmcnt(0)" ::: "memory");
        __builtin_amdgcn_s_barrier();
        __builtin_amdgcn_sched_barrier(0);
        kcur = kcur + 1; if (kcur >= 3) kcur -= 3;
    }

    // final deferred PV (last barrier was vmcnt(0): V(niter-1) resident)
    {
        const char* vb = Vtile[(niter - 1) & 1];
        for (int cb = 0; cb < 16; ++cb) {
            int row = cb * 16 + l15;
            long vf = *(const long*)(vb + row * 32 + (((lg ^ (row >> 2)) & 3) << 3));
            O[0][cb] = __builtin_amdgcn_mfma_f32_16x16x32_fp8_fp8(pap0, vf, O[0][cb], 0, 0, 0);
            O[1][cb] = __builtin_amdgcn_mfma_f32_16x16x32_fp8_fp8(pap1, vf, O[1][cb], 0, 0, 0);
        }
    }

    for (int qf = 0; qf < 2; ++qf) {
        lsum[qf] += __shfl_xor(lsum[qf], 16);
        lsum[qf] += __shfl_xor(lsum[qf], 32);
    }

    unsigned short* Ob = Opart + (size_t)(b * nsplit + split) * N_ * C_;
    float* mlb = ml + (size_t)(b * nsplit + split) * N_ * 2;
    for (int qf = 0; qf < 2; ++qf)
        for (int cb = 0; cb < 16; ++cb)
            for (int r = 0; r < 4; ++r)
                Ob[(size_t)(n0 + qf * 16 + lg * 4 + r) * C_ + cb * 16 + l15] =
                    f2bf(qf == 0 ? O[0][cb][r] : O[1][cb][r]);
    if (lane < 16)
        for (int qf = 0; qf < 2; ++qf) {
            int n = n0 + qf * 16 + lane;
            mlb[n * 2] = mrun[qf];
            mlb[n * 2 + 1] = lsum[qf];
        }
}

// ---------------- merge partials -> ao bf16 [b][n][c], vectorized 16B/lane ----------------
__global__ __launch_bounds__(256) void attn_merge_kernel(const unsigned short* __restrict__ Opart,
                                                         const float* __restrict__ ml,
                                                         unsigned short* __restrict__ ao,
                                                         int nsplit) {
    int b = blockIdx.y;
    int n0 = blockIdx.x * 16;
    int t = threadIdx.x;
    int chunk = t & 31, rsub = t >> 5;     // 32 c-chunks of 8; 8 rows per pass
    for (int p = 0; p < 2; ++p) {
        int n = n0 + p * 8 + rsub;
        float M = -1e30f;
        for (int s = 0; s < nsplit; ++s)
            M = fmaxf(M, ml[((size_t)(b * nsplit + s) * N_ + n) * 2]);
        float L = 0.f;
        float o[8];
        for (int j = 0; j < 8; ++j) o[j] = 0.f;
        for (int s = 0; s < nsplit; ++s) {
            const float* mlp = ml + ((size_t)(b * nsplit + s) * N_ + n) * 2;
            float wgt = __builtin_amdgcn_exp2f(mlp[0] - M);
            L += mlp[1] * wgt;
            s16x8 v = *(const s16x8*)(Opart + ((size_t)(b * nsplit + s) * N_ + n) * C_ + chunk * 8);
            for (int j = 0; j < 8; ++j) o[j] += bf2f((unsigned short)v[j]) * wgt;
        }
        float rL = 1.f / L;
        s16x8 pk;
        for (int j = 0; j < 8; ++j) pk[j] = (short)f2bf(o[j] * rL);
        *(s16x8*)(ao + ((size_t)b * N_ + n) * C_ + chunk * 8) = pk;
    }
}

extern "C" void kernel_launch(void* const* d_in, const int* in_sizes, int n_in,
                              void* d_out, int out_size, void* d_ws, size_t ws_size,
                              hipStream_t stream) {
    const float* x = (const float*)d_in[0];
    const float* gamma = (const float*)d_in[1];
    const float* beta = (const float*)d_in[2];
    const float* wq = (const float*)d_in[3];
    const float* bq = (const float*)d_in[4];
    const float* wk = (const float*)d_in[5];
    const float* bk = (const float*)d_in[6];
    const float* wv = (const float*)d_in[7];
    const float* bv = (const float*)d_in[8];
    const float* wp = (const float*)d_in[9];
    const float* bp = (const float*)d_in[10];
    float* out = (float*)d_out;

    const size_t sz = (size_t)B_ * N_ * C_;
    unsigned short* hn = (unsigned short*)d_ws;  // [b][n][c]
    unsigned short* qt = hn + sz;                // [b][n][c], scaled by log2e/16
    unsigned short* kt = qt + sz;                // k3t slot layout bf16 (swizzled)
    unsigned short* v2t = kt + sz;               // fp8 V region (sz bytes used)
    unsigned short* ao = v2t + sz;               // [b][n][c]
    unsigned short* wbf = ao + sz;               // 4 x 256 x 256 bf16
    unsigned short* Opart = wbf + 4 * 65536;     // [b][s][n][c] bf16
    int nsplit = 8;
    while (nsplit > 1 &&
           (5 * sz + 262144 + (size_t)nsplit * sz) * 2 + (size_t)nsplit * B_ * N_ * 8 + 4096 > ws_size)
        nsplit >>= 1;
    float* ml = (float*)(Opart + (size_t)nsplit * sz);   // [b][s][n][2]
    float* part = ml + (size_t)nsplit * B_ * N_ * 2;     // [256][2] GN partials

    hipLaunchKernelGGL(gn_stats_kernel, dim3(320), dim3(256), 0, stream, x, part,
                       wq, wk, wv, wp, wbf);
    hipLaunchKernelGGL(gn_apply_kernel, dim3(256), dim3(256), 0, stream, x, gamma, beta, part, hn);
    hipLaunchKernelGGL(qkv_gemm_kernel, dim3(64, 2, 6), dim3(256), 0, stream,
                       wbf, bq, bk, bv, hn, qt, kt, (unsigned char*)v2t);
    hipLaunchKernelGGL(attn_partial_kernel, dim3(32, nsplit, 2), dim3(256), 0, stream,
                       qt, kt, (const unsigned char*)v2t, Opart, ml, N_ / nsplit);
    hipLaunchKernelGGL(attn_merge_kernel, dim3(N_ / 16, 2), dim3(256), 0, stream, Opart, ml, ao, nsplit);
    hipLaunchKernelGGL(proj_gemm_kernel, dim3(64, 2, 2), dim3(256), 0, stream, wbf, bp, ao, x, out);
}